// Round 3
// baseline (789.453 us; speedup 1.0000x reference)
//
#include <hip/hip_runtime.h>

namespace {

typedef __attribute__((ext_vector_type(8))) short short8;   // 8 bf16 (4 VGPRs)
typedef __attribute__((ext_vector_type(4))) float f32x4;

constexpr int T_LEN = 512;
constexpr int TC    = 16;    // timesteps per x-staging chunk
constexpr int HSTR  = 40;    // h-plane row stride (shorts): 32 used + 8 pad, 80B (16B-mult)
constexpr int XSTR  = 264;   // x-plane row stride (shorts): 256 used + 8 pad, 528B (16B-mult)

__device__ __forceinline__ float fsig(float x) {
    return __builtin_amdgcn_rcpf(1.0f + __expf(-x));
}
__device__ __forceinline__ float ftanh(float x) {
    return 2.0f * __builtin_amdgcn_rcpf(1.0f + __expf(-2.0f * x)) - 1.0f;
}
__device__ __forceinline__ f32x4 mfma16(short8 a, short8 b, f32x4 c) {
    return __builtin_amdgcn_mfma_f32_16x16x32_bf16(a, b, c, 0, 0, 0);
}
// pack bf16-truncations of (a,b) into one dword, b in LOW short
__device__ __forceinline__ unsigned permhi(float a, float b) {
    return __builtin_amdgcn_perm(__float_as_uint(a), __float_as_uint(b), 0x07060302u);
}
__device__ __forceinline__ float lo_resid(float v) {
    return v - __uint_as_float(__float_as_uint(v) & 0xffff0000u);
}
__device__ __forceinline__ short hi16(float v) {
    return (short)(__float_as_uint(v) >> 16);
}

// block = 512 threads = 8 waves over the SAME 16 batch rows.
// wid bits: [2]=layer (0=L1 step t, 1=L2 step t-1), [1]=unit parity p, [0]=K-half s.
// K-SPLIT (no MFMA duplication): the 6-term accumulation per gate splits 3+3:
//   s0: bias + a0h*B0h + a1h*B1h + a0l*B0h      (term order preserved)
//   s1:        a1l*B1h + a0h*B0l + a1h*B1l      (term order preserved)
// Partials exchanged via LDS pbuf (barrier #2); each wave then finishes the
// elementwise for only 2 of the 4 accumulator rows (s0: rows 0,1; s1: rows 2,3).
// Per SIMD: 2 waves x 12 MFMAs = same matrix work as the 4-wave kernel, VALU split
// 2 ways for latency hiding. Only numerics change: one f32 reassociation (~ulp).
__global__ __launch_bounds__(512)
void lstm2_ksplit_kernel(const float* __restrict__ x,
                         const float* __restrict__ Wih0, const float* __restrict__ Whh0,
                         const float* __restrict__ bih0, const float* __restrict__ bhh0,
                         const float* __restrict__ Wih1, const float* __restrict__ Whh1,
                         const float* __restrict__ bih1, const float* __restrict__ bhh1,
                         const float* __restrict__ W1, const float* __restrict__ b1,
                         const float* __restrict__ W2, const float* __restrict__ b2,
                         float* __restrict__ out)
{
    __shared__ __align__(16) short sh1hi[2][16 * HSTR], sh1lo[2][16 * HSTR]; // h1 ring
    __shared__ __align__(16) short sh2hi[2][16 * HSTR], sh2lo[2][16 * HSTR]; // h2 ring
    __shared__ __align__(16) short sxhi[16 * XSTR],     sxlo[16 * XSTR];     // x chunk
    __shared__ __align__(16) unsigned szero[8];                              // zero pad
    __shared__ __align__(16) float pbuf[2][2][2][4][64][2];                  // partial acc, 16 KB

    const int tid  = threadIdx.x;
    const int wid  = tid >> 6;
    const int lane = tid & 63;
    const int q    = lane >> 4;          // quad
    const int n    = lane & 15;          // MFMA col (B) / batch row (A)
    const int layer = wid >> 2;          // 0 = L1, 1 = L2
    const bool isL1 = (layer == 0);
    const int p    = (wid >> 1) & 1;     // unit parity owned by this wave pair
    const int s    = wid & 1;            // K-half / row-half owned by this wave

    // ---- zero h planes ----
    for (int i = tid; i < 16 * HSTR; i += 512) {
        sh1hi[0][i] = 0; sh1hi[1][i] = 0; sh1lo[0][i] = 0; sh1lo[1][i] = 0;
        sh2hi[0][i] = 0; sh2hi[1][i] = 0; sh2lo[0][i] = 0; sh2lo[1][i] = 0;
    }
    if (tid < 8) szero[tid] = 0u;

    // ---- per-wave persistent weight B-fragments + bias C-operands ----
    // chunk for gate g covers unit cols 2n+p. K-map frag0 k=0..31, frag1 k=32..63:
    // L1: frag0 = Whh0, frag1 = [Wih0 | 0];  L2: frag0 = Wih1, frag1 = Whh1.
    // s0 holds: wX = frag0-hi, wY = frag1-hi (wZ dead).
    // s1 holds: wX = frag0-lo, wY = frag1-lo, wZ = frag1-hi.
    short8 wX[4], wY[4], wZ[4];
    f32x4  bsp[4];
    #pragma unroll
    for (int gate = 0; gate < 4; ++gate) {
        const int row = gate * 32 + 2 * n + p;
        #pragma unroll
        for (int f = 0; f < 2; ++f) {
            #pragma unroll
            for (int e = 0; e < 8; ++e) {
                const int kk = f * 32 + q * 8 + e;
                float v;
                if (isL1) v = (kk < 32) ? Whh0[row * 32 + kk]
                            : (kk < 48) ? Wih0[row * 16 + (kk - 32)] : 0.0f;
                else      v = (kk < 32) ? Wih1[row * 32 + kk]
                                        : Whh1[row * 32 + (kk - 32)];
                const unsigned b = __float_as_uint(v);
                const short hi = (short)(b >> 16);
                const float hif = __uint_as_float(b & 0xffff0000u);
                const short lo = (short)(__float_as_uint(v - hif) >> 16);
                const short w  = s ? lo : hi;
                if (f == 0) wX[gate][e] = w;
                else        { wY[gate][e] = w; wZ[gate][e] = hi; }
            }
        }
        const float bv = isL1 ? (bih0[row] + bhh0[row]) : (bih1[row] + bhh1[row]);
        const float bs = s ? 0.0f : bv;
        bsp[gate] = (f32x4){bs, bs, bs, bs};
    }

    float cst[2];                        // c-state for this wave's 2 rows x parity-p unit
    cst[0] = 0.f; cst[1] = 0.f;

    const float4* xg = (const float4*)x + (size_t)blockIdx.x * 16 * (T_LEN * 4);

    #pragma unroll 1
    for (int i = 0; i <= T_LEN; ++i) {
        if (i < T_LEN && (i & (TC - 1)) == 0) {
            __syncthreads();            // prior chunk's reads (iter i-1) are done
            // stage x[t0 = i .. i+15] into hi/lo planes (all 8 waves help)
            const int b = tid & 15, w = tid >> 4;     // batch row, 32 threads/row
            const float4* src = xg + (size_t)b * (T_LEN * 4) + (size_t)i * 4;
            short* dh = &sxhi[b * XSTR];
            short* dl = &sxlo[b * XSTR];
            #pragma unroll
            for (int ii = 0; ii < 2; ++ii) {
                const int el = w + ii * 32;           // float4 index within chunk row
                const float4 v = src[el];
                uint2 hp, lp;
                hp.x = permhi(v.y, v.x);
                hp.y = permhi(v.w, v.z);
                lp.x = permhi(lo_resid(v.y), lo_resid(v.x));
                lp.y = permhi(lo_resid(v.w), lo_resid(v.z));
                *(uint2*)&dh[el * 4] = hp;
                *(uint2*)&dl[el * 4] = lp;
            }
        }
        __syncthreads();                // barrier 1: h(t-1) + x visible

        const bool active = isL1 ? (i < T_LEN) : (i >= 1);
        const int t = isL1 ? i : (i - 1);
        short *dhi, *dlo;
        {
            if (isL1) { dhi = sh1hi[t & 1]; dlo = sh1lo[t & 1]; }
            else      { dhi = sh2hi[t & 1]; dlo = sh2lo[t & 1]; }
        }

        float gown[4][2];               // this wave's 2 owned rows, per gate
        if (active) {
            const short *pa0h, *pa0l, *pa1h, *pa1l;
            if (isL1) {
                const int ps = (t + 1) & 1;           // slot holding h1_{t-1}
                const int tt = t & (TC - 1);
                pa0h = &sh1hi[ps][n * HSTR + q * 8];
                pa0l = &sh1lo[ps][n * HSTR + q * 8];
                pa1h = (q < 2) ? &sxhi[n * XSTR + tt * 16 + q * 8] : (const short*)szero;
                pa1l = (q < 2) ? &sxlo[n * XSTR + tt * 16 + q * 8] : (const short*)szero;
            } else {
                const int s1  = t & 1;                // slot holding h1_t
                const int ps2 = (t + 1) & 1;          // slot holding h2_{t-1}
                pa0h = &sh1hi[s1][n * HSTR + q * 8];
                pa0l = &sh1lo[s1][n * HSTR + q * 8];
                pa1h = &sh2hi[ps2][n * HSTR + q * 8];
                pa1l = &sh2lo[ps2][n * HSTR + q * 8];
            }
            const short8 a0h = *(const short8*)pa0h;
            const short8 a0l = *(const short8*)pa0l;
            const short8 a1h = *(const short8*)pa1h;
            const short8 a1l = *(const short8*)pa1l;

            #pragma unroll
            for (int gate = 0; gate < 4; ++gate) {
                f32x4 acc;
                if (s == 0) {
                    acc = mfma16(a0h, wX[gate], bsp[gate]);
                    acc = mfma16(a1h, wY[gate], acc);
                    acc = mfma16(a0l, wX[gate], acc);
                } else {
                    acc = mfma16(a1l, wZ[gate], bsp[gate]);   // bsp = 0 for s1
                    acc = mfma16(a0h, wX[gate], acc);
                    acc = mfma16(a1h, wY[gate], acc);
                }
                float* pb = &pbuf[layer][p][s][gate][lane][0];
                if (s == 0) {
                    gown[gate][0] = acc[0]; gown[gate][1] = acc[1];
                    pb[0] = acc[2]; pb[1] = acc[3];   // donate rows 2,3
                } else {
                    gown[gate][0] = acc[2]; gown[gate][1] = acc[3];
                    pb[0] = acc[0]; pb[1] = acc[1];   // donate rows 0,1
                }
            }
        }
        __syncthreads();                // barrier 2: partials visible

        if (active) {
            float rda[4][2];
            #pragma unroll
            for (int gate = 0; gate < 4; ++gate) {
                const float* pb = &pbuf[layer][p][s ^ 1][gate][lane][0];
                rda[gate][0] = pb[0]; rda[gate][1] = pb[1];
            }
            #pragma unroll
            for (int r = 0; r < 2; ++r) {
                const float ig = fsig(gown[0][r] + rda[0][r]);
                const float fg = fsig(gown[1][r] + rda[1][r]);
                const float gg = ftanh(gown[2][r] + rda[2][r]);
                const float og = fsig(gown[3][r] + rda[3][r]);
                const float cc = fg * cst[r] + ig * gg;
                cst[r] = cc;
                const float hv = og * ftanh(cc);
                const int ro = (q * 4 + 2 * s + r) * HSTR + 2 * n + p;
                dhi[ro] = hi16(hv);
                dlo[ro] = hi16(lo_resid(hv));
            }
        }
    }

    // ---- MLP head on h2_{T-1} (slot (T_LEN-1)&1 = 1) ----
    __syncthreads();
    if (wid == 4 && lane < 16) {
        const int fs = (T_LEN - 1) & 1;
        float h2v[32];
        #pragma unroll
        for (int kk = 0; kk < 32; ++kk) {
            h2v[kk] = __uint_as_float(((unsigned)(unsigned short)sh2hi[fs][lane * HSTR + kk]) << 16)
                    + __uint_as_float(((unsigned)(unsigned short)sh2lo[fs][lane * HSTR + kk]) << 16);
        }
        float pacc = b2[0];
        #pragma unroll 1
        for (int jj = 0; jj < 16; ++jj) {
            float acc = b1[jj];
            #pragma unroll
            for (int kk = 0; kk < 32; ++kk) acc += W1[jj * 32 + kk] * h2v[kk];
            pacc += W2[jj] * fmaxf(acc, 0.f);
        }
        out[blockIdx.x * 16 + lane] = pacc;
    }
}

} // namespace

extern "C" void kernel_launch(void* const* d_in, const int* in_sizes, int n_in,
                              void* d_out, int out_size, void* d_ws, size_t ws_size,
                              hipStream_t stream) {
    const float* x    = (const float*)d_in[0];
    const float* Wih0 = (const float*)d_in[1];
    const float* Whh0 = (const float*)d_in[2];
    const float* bih0 = (const float*)d_in[3];
    const float* bhh0 = (const float*)d_in[4];
    const float* Wih1 = (const float*)d_in[5];
    const float* Whh1 = (const float*)d_in[6];
    const float* bih1 = (const float*)d_in[7];
    const float* bhh1 = (const float*)d_in[8];
    const float* W1   = (const float*)d_in[9];
    const float* b1   = (const float*)d_in[10];
    const float* W2   = (const float*)d_in[11];
    const float* b2   = (const float*)d_in[12];

    const int batch  = out_size;            // 4096
    const int blocks = batch / 16;          // 256 blocks x 8 waves

    hipLaunchKernelGGL(lstm2_ksplit_kernel, dim3(blocks), dim3(512), 0, stream,
                       x, Wih0, Whh0, bih0, bhh0, Wih1, Whh1, bih1, bhh1,
                       W1, b1, W2, b2, (float*)d_out);
}

// Round 5
// 655.560 us; speedup vs baseline: 1.2042x; 1.2042x over previous
//
#include <hip/hip_runtime.h>

namespace {

typedef __attribute__((ext_vector_type(8))) short short8;   // 8 bf16 (4 VGPRs)
typedef __attribute__((ext_vector_type(4))) float f32x4;

constexpr int T_LEN = 512;
constexpr int HSTR  = 40;    // h-plane row stride (shorts): 32 used + 8 pad, 80B (16B-mult)

__device__ __forceinline__ float fsig(float x) {
    return __builtin_amdgcn_rcpf(1.0f + __expf(-x));
}
__device__ __forceinline__ float ftanh(float x) {
    return 2.0f * __builtin_amdgcn_rcpf(1.0f + __expf(-2.0f * x)) - 1.0f;
}
__device__ __forceinline__ f32x4 mfma16(short8 a, short8 b, f32x4 c) {
    return __builtin_amdgcn_mfma_f32_16x16x32_bf16(a, b, c, 0, 0, 0);
}
// pack bf16-truncations of (a,b) into one dword, b in LOW short
__device__ __forceinline__ unsigned permhi(float a, float b) {
    return __builtin_amdgcn_perm(__float_as_uint(a), __float_as_uint(b), 0x07060302u);
}
__device__ __forceinline__ float lo_resid(float v) {
    return v - __uint_as_float(__float_as_uint(v) & 0xffff0000u);
}
__device__ __forceinline__ short hi16(float v) {
    return (short)(__float_as_uint(v) >> 16);
}

__device__ __forceinline__ void load_x(int q, const float4* xg4, int n, int t,
                                       float4& ra, float4& rb) {
    if (q < 2) {
        const float4* s = xg4 + (size_t)n * (T_LEN * 4) + (size_t)t * 4 + 2 * q;
        ra = s[0]; rb = s[1];
    }
}

__device__ __forceinline__ void pack_x(int q, const float4& va, const float4& vb,
                                       short8& xh8, short8& xl8) {
    if (q < 2) {
        union { short8 s; uint4 u; } h, l;
        h.u.x = permhi(va.y, va.x); h.u.y = permhi(va.w, va.z);
        h.u.z = permhi(vb.y, vb.x); h.u.w = permhi(vb.w, vb.z);
        l.u.x = permhi(lo_resid(va.y), lo_resid(va.x));
        l.u.y = permhi(lo_resid(va.w), lo_resid(va.z));
        l.u.z = permhi(lo_resid(vb.y), lo_resid(vb.x));
        l.u.w = permhi(lo_resid(vb.w), lo_resid(vb.z));
        xh8 = h.s; xl8 = l.s;
    }
}

__device__ __forceinline__ void ew_write(const f32x4 (&gg)[4], float (&cst)[4],
                                         short* dhi, short* dlo, int q, int n, int p) {
    #pragma unroll
    for (int r = 0; r < 4; ++r) {
        const float ig = fsig(gg[0][r]);
        const float fg = fsig(gg[1][r]);
        const float gv = ftanh(gg[2][r]);
        const float og = fsig(gg[3][r]);
        const float cc = fg * cst[r] + ig * gv;
        cst[r] = cc;
        const float hv = og * ftanh(cc);
        const int ro = (q * 4 + r) * HSTR + 2 * n + p;
        dhi[ro] = hi16(hv);
        dlo[ro] = hi16(lo_resid(hv));
    }
}

// block = 256 threads = 4 waves over the SAME 16 batch rows.
// waves 0,1 = layer-1 (parity p = wid&1), waves 2,3 = layer-2 (p = wid&1) + MLP head.
// L1 x-terms (Wih0*x_t + bias) are NOT recurrent: precomputed 2 steps ahead into
// register pre-banks via 12 filler MFMAs/step, with x loaded global->regs (4-step
// prefetch). L1 critical path = 2 ds_reads + 12 MFMAs + EW. L2 unchanged except its
// 6-deep MFMA chain splits into two independent 3-chains + f32x4 add.
// Main loop unrolled x4: all ring slots / pre-bank indices are compile-time constants.
// NOTE: all ring-slot parities derive as (k+1)&1 / k&1 — NOT k^1 (k runs 0..3; k^1
// gave 3,2 for k=2,3 and indexed off the [2] rings — the R3 correctness bug).
// One barrier per step. Numerics vs R1 kernel: f32 reassociation only (~ulp).
__global__ __launch_bounds__(256)
void lstm2_pre_kernel(const float* __restrict__ x,
                      const float* __restrict__ Wih0, const float* __restrict__ Whh0,
                      const float* __restrict__ bih0, const float* __restrict__ bhh0,
                      const float* __restrict__ Wih1, const float* __restrict__ Whh1,
                      const float* __restrict__ bih1, const float* __restrict__ bhh1,
                      const float* __restrict__ W1, const float* __restrict__ b1,
                      const float* __restrict__ W2, const float* __restrict__ b2,
                      float* __restrict__ out)
{
    __shared__ __align__(16) short sh1hi[2][16 * HSTR], sh1lo[2][16 * HSTR]; // h1 ring
    __shared__ __align__(16) short sh2hi[2][16 * HSTR], sh2lo[2][16 * HSTR]; // h2 ring

    const int tid  = threadIdx.x;
    const int wid  = tid >> 6;           // 0,1 = L1; 2,3 = L2
    const int lane = tid & 63;
    const int q    = lane >> 4;          // quad
    const int n    = lane & 15;          // MFMA col (B) / batch row (A)
    const bool isL1 = (wid < 2);
    const int p    = wid & 1;            // unit parity owned by this wave

    // ---- zero h planes ----
    for (int i = tid; i < 16 * HSTR; i += 256) {
        sh1hi[0][i] = 0; sh1hi[1][i] = 0; sh1lo[0][i] = 0; sh1lo[1][i] = 0;
        sh2hi[0][i] = 0; sh2hi[1][i] = 0; sh2lo[0][i] = 0; sh2lo[1][i] = 0;
    }

    // ---- per-wave persistent weight B-fragments + bias C-operands ----
    // chunk for gate g covers unit cols 2n+p.
    // L1: bh/bl[g][0] = Whh0 (K=0..31), bh/bl[g][1] = [Wih0 (k<16) | 0]  (pre-B-frag)
    // L2: bh/bl[g][0] = Wih1 (h1-terms), bh/bl[g][1] = Whh1 (h2-terms)
    short8 bh[4][2], bl[4][2];
    f32x4  bsp[4];
    #pragma unroll
    for (int gate = 0; gate < 4; ++gate) {
        const int row = gate * 32 + 2 * n + p;
        #pragma unroll
        for (int f = 0; f < 2; ++f) {
            #pragma unroll
            for (int e = 0; e < 8; ++e) {
                const int kk = f * 32 + q * 8 + e;
                float v;
                if (isL1) v = (kk < 32) ? Whh0[row * 32 + kk]
                            : (kk < 48) ? Wih0[row * 16 + (kk - 32)] : 0.0f;
                else      v = (kk < 32) ? Wih1[row * 32 + kk]
                                        : Whh1[row * 32 + (kk - 32)];
                const unsigned b = __float_as_uint(v);
                bh[gate][f][e] = (short)(b >> 16);
                const float hif = __uint_as_float(b & 0xffff0000u);
                bl[gate][f][e] = (short)(__float_as_uint(v - hif) >> 16);
            }
        }
        const float bv = isL1 ? (bih0[row] + bhh0[row]) : (bih1[row] + bhh1[row]);
        bsp[gate] = (f32x4){bv, bv, bv, bv};
    }

    float cst[4];                        // c-state (c1 for L1 waves, c2 for L2 waves)
    #pragma unroll
    for (int r = 0; r < 4; ++r) cst[r] = 0.f;

    const float4* xg4 = (const float4*)x + (size_t)blockIdx.x * 16 * (T_LEN * 4);

    // ---- L1 prologue: build pre(0), pre(1); prefetch x(2), x(3) ----
    float4 r0a{}, r0b{}, r1a{}, r1b{};
    short8 xh0 = (short8)(short)0, xl0 = (short8)(short)0;
    short8 xh1 = (short8)(short)0, xl1 = (short8)(short)0;
    f32x4 pA0[4], pA1[4], pB0[4], pB1[4];
    if (isL1) {
        load_x(q, xg4, n, 0, r0a, r0b);
        load_x(q, xg4, n, 1, r1a, r1b);
        pack_x(q, r0a, r0b, xh0, xl0);
        pack_x(q, r1a, r1b, xh1, xl1);
        #pragma unroll
        for (int g2 = 0; g2 < 4; ++g2) {
            f32x4 c = mfma16(xh0, bh[g2][1], bsp[g2]);
            c = mfma16(xl0, bh[g2][1], c);
            c = mfma16(xh0, bl[g2][1], c);
            pA0[g2] = c;
            f32x4 d = mfma16(xh1, bh[g2][1], bsp[g2]);
            d = mfma16(xl1, bh[g2][1], d);
            d = mfma16(xh1, bl[g2][1], d);
            pA1[g2] = d;
        }
        load_x(q, xg4, n, 2, r0a, r0b);
        load_x(q, xg4, n, 3, r1a, r1b);
    }

    __syncthreads();                     // h-plane zeros visible

    #pragma unroll 1
    for (int i = 0; i < T_LEN; i += 4) {
        #pragma unroll
        for (int k = 0; k < 4; ++k) {
            const int t = i + k;
            if (isL1) {
                // pack x(t+2) (loaded 2 steps ago) for the pre-build below
                const bool more = (i + k + 2 < T_LEN);
                if (more) {
                    if ((k & 1) == 0) pack_x(q, r0a, r0b, xh0, xl0);
                    else              pack_x(q, r1a, r1b, xh1, xl1);
                }
                // recurrent part: h-terms only, C-init = pre[t]
                const int RS = (k + 1) & 1, WS = k & 1;   // ring slots (static)
                const short8 a0h = *(const short8*)&sh1hi[RS][n * HSTR + q * 8];
                const short8 a0l = *(const short8*)&sh1lo[RS][n * HSTR + q * 8];
                f32x4 gg[4];
                #pragma unroll
                for (int g2 = 0; g2 < 4; ++g2) {
                    f32x4 c = (k == 0) ? pA0[g2] : (k == 1) ? pA1[g2]
                            : (k == 2) ? pB0[g2] : pB1[g2];
                    c = mfma16(a0h, bh[g2][0], c);
                    c = mfma16(a0l, bh[g2][0], c);
                    c = mfma16(a0h, bl[g2][0], c);
                    gg[g2] = c;
                }
                ew_write(gg, cst, &sh1hi[WS][0], &sh1lo[WS][0], q, n, p);
                // filler: build pre(t+2) into the opposite bank; prefetch x(t+4)
                if (more) {
                    const short8 xh = (k & 1) ? xh1 : xh0;
                    const short8 xl = (k & 1) ? xl1 : xl0;
                    #pragma unroll
                    for (int g2 = 0; g2 < 4; ++g2) {
                        f32x4 c = mfma16(xh, bh[g2][1], bsp[g2]);
                        c = mfma16(xl, bh[g2][1], c);
                        c = mfma16(xh, bl[g2][1], c);
                        if (k == 0)      pB0[g2] = c;
                        else if (k == 1) pB1[g2] = c;
                        else if (k == 2) pA0[g2] = c;
                        else             pA1[g2] = c;
                    }
                    const int tn = (t + 4 < T_LEN) ? (t + 4) : (T_LEN - 1);
                    if ((k & 1) == 0) load_x(q, xg4, n, tn, r0a, r0b);
                    else              load_x(q, xg4, n, tn, r1a, r1b);
                }
            } else {
                if (i + k >= 1) {                         // t2 = t-1
                    const int S1 = (k + 1) & 1;           // slot holding h1_{t-1}
                    const int PS2 = k & 1;                // slot holding h2_{t-2}
                    const int W2 = (k + 1) & 1;           // slot receiving h2_{t-1}
                    const short8 a0h = *(const short8*)&sh1hi[S1][n * HSTR + q * 8];
                    const short8 a0l = *(const short8*)&sh1lo[S1][n * HSTR + q * 8];
                    const short8 a1h = *(const short8*)&sh2hi[PS2][n * HSTR + q * 8];
                    const short8 a1l = *(const short8*)&sh2lo[PS2][n * HSTR + q * 8];
                    f32x4 gg[4];
                    #pragma unroll
                    for (int g2 = 0; g2 < 4; ++g2) {
                        f32x4 c1 = mfma16(a0h, bh[g2][0], bsp[g2]);
                        c1 = mfma16(a0l, bh[g2][0], c1);
                        c1 = mfma16(a0h, bl[g2][0], c1);
                        f32x4 c2 = mfma16(a1h, bh[g2][1], (f32x4){0.f, 0.f, 0.f, 0.f});
                        c2 = mfma16(a1l, bh[g2][1], c2);
                        c2 = mfma16(a1h, bl[g2][1], c2);
                        gg[g2] = c1 + c2;
                    }
                    ew_write(gg, cst, &sh2hi[W2][0], &sh2lo[W2][0], q, n, p);
                }
            }
            __syncthreads();
        }
    }

    // ---- epilogue: L2 for t2 = 511 (slots: S1=1, PS2=0, W2=1) ----
    if (!isL1) {
        const short8 a0h = *(const short8*)&sh1hi[1][n * HSTR + q * 8];
        const short8 a0l = *(const short8*)&sh1lo[1][n * HSTR + q * 8];
        const short8 a1h = *(const short8*)&sh2hi[0][n * HSTR + q * 8];
        const short8 a1l = *(const short8*)&sh2lo[0][n * HSTR + q * 8];
        f32x4 gg[4];
        #pragma unroll
        for (int g2 = 0; g2 < 4; ++g2) {
            f32x4 c1 = mfma16(a0h, bh[g2][0], bsp[g2]);
            c1 = mfma16(a0l, bh[g2][0], c1);
            c1 = mfma16(a0h, bl[g2][0], c1);
            f32x4 c2 = mfma16(a1h, bh[g2][1], (f32x4){0.f, 0.f, 0.f, 0.f});
            c2 = mfma16(a1l, bh[g2][1], c2);
            c2 = mfma16(a1h, bl[g2][1], c2);
            gg[g2] = c1 + c2;
        }
        ew_write(gg, cst, &sh2hi[1][0], &sh2lo[1][0], q, n, p);
    }
    __syncthreads();

    // ---- MLP head on h2_{T-1} (slot 1) ----
    if (wid == 2 && lane < 16) {
        float h2v[32];
        #pragma unroll
        for (int kk = 0; kk < 32; ++kk) {
            h2v[kk] = __uint_as_float(((unsigned)(unsigned short)sh2hi[1][lane * HSTR + kk]) << 16)
                    + __uint_as_float(((unsigned)(unsigned short)sh2lo[1][lane * HSTR + kk]) << 16);
        }
        float pacc = b2[0];
        #pragma unroll 1
        for (int jj = 0; jj < 16; ++jj) {
            float acc = b1[jj];
            #pragma unroll
            for (int kk = 0; kk < 32; ++kk) acc += W1[jj * 32 + kk] * h2v[kk];
            pacc += W2[jj] * fmaxf(acc, 0.f);
        }
        out[blockIdx.x * 16 + lane] = pacc;
    }
}

} // namespace

extern "C" void kernel_launch(void* const* d_in, const int* in_sizes, int n_in,
                              void* d_out, int out_size, void* d_ws, size_t ws_size,
                              hipStream_t stream) {
    const float* x    = (const float*)d_in[0];
    const float* Wih0 = (const float*)d_in[1];
    const float* Whh0 = (const float*)d_in[2];
    const float* bih0 = (const float*)d_in[3];
    const float* bhh0 = (const float*)d_in[4];
    const float* Wih1 = (const float*)d_in[5];
    const float* Whh1 = (const float*)d_in[6];
    const float* bih1 = (const float*)d_in[7];
    const float* bhh1 = (const float*)d_in[8];
    const float* W1   = (const float*)d_in[9];
    const float* b1   = (const float*)d_in[10];
    const float* W2   = (const float*)d_in[11];
    const float* b2   = (const float*)d_in[12];

    const int batch  = out_size;            // 4096
    const int blocks = batch / 16;          // 256 blocks x 4 waves

    hipLaunchKernelGGL(lstm2_pre_kernel, dim3(blocks), dim3(256), 0, stream,
                       x, Wih0, Whh0, bih0, bhh0, Wih1, Whh1, bih1, bhh1,
                       W1, b1, W2, b2, (float*)d_out);
}